// Round 5
// baseline (462.152 us; speedup 1.0000x reference)
//
#include <hip/hip_runtime.h>
#include <hip/hip_bf16.h>

typedef __bf16 bf16_t;
typedef __bf16 bf16x8 __attribute__((ext_vector_type(8)));
typedef __bf16 bf16x4 __attribute__((ext_vector_type(4)));
typedef float  f32x4  __attribute__((ext_vector_type(4)));

#define D_DIM 1024
#define N_LAB 64
#define ST_TOK 16384
#define QT_TOK 16384
#define TSPLIT 32
#define TSLICE (ST_TOK / TSPLIT)   // 512 tokens per slice

// ---------------- Kernel 1: proto partials + fused last-block finalize ----
// grid = 2048 blocks: blockIdx = (ts<<6) | label. Each block scans its
// 512-token slice for (mask && tag==label), streams matching FULL rows
// (thread owns dims tid*4..+3) into registers, writes one fp32 partial row
// + count. Then: __threadfence + atomicAdd(done[label]); the last of the 32
// blocks for a label sums the partials, divides by count, emits bf16 proto
// + p2 partials (k_pfinal folded in; kernel boundary then publishes to k_logits).
__global__ __launch_bounds__(256) void k_proto(
    const float* __restrict__ s_emb, const int* __restrict__ tag,
    const int* __restrict__ msk, float* __restrict__ part,
    int* __restrict__ cntPart, int* __restrict__ done,
    bf16_t* __restrict__ protoB, float* __restrict__ p2part)
{
    __shared__ int list[TSLICE];
    __shared__ int cnt;
    __shared__ int lastFlag;
    __shared__ float red[4];

    const int tid   = threadIdx.x;
    const int lane  = tid & 63;
    const int wave  = tid >> 6;
    const int label = blockIdx.x & 63;
    const int ts    = blockIdx.x >> 6;

    if (tid == 0) cnt = 0;
    __syncthreads();

    const int t0 = ts * TSLICE;
    for (int i = tid; i < TSLICE; i += 256) {
        const int t = t0 + i;
        if (msk[t] && tag[t] == label) list[atomicAdd(&cnt, 1)] = t;
    }
    __syncthreads();
    const int n = cnt;

    f32x4 acc = {0.f, 0.f, 0.f, 0.f};
    const float* base = s_emb + tid * 4;
    int i = 0;
    for (; i + 2 <= n; i += 2) {
        f32x4 v0 = *(const f32x4*)(base + (size_t)list[i]     * D_DIM);
        f32x4 v1 = *(const f32x4*)(base + (size_t)list[i + 1] * D_DIM);
        acc += v0;
        acc += v1;
    }
    if (i < n) acc += *(const f32x4*)(base + (size_t)list[i] * D_DIM);

    *(f32x4*)(part + ((size_t)ts * N_LAB + label) * D_DIM + tid * 4) = acc;
    if (tid == 0) cntPart[ts * N_LAB + label] = n;

    // ---- last-block-per-label finalize ----
    __threadfence();                               // publish part + cntPart
    if (tid == 0)
        lastFlag = (atomicAdd(&done[label], 1) == TSPLIT - 1);
    __syncthreads();
    if (!lastFlag) return;
    __threadfence();                               // acquire others' writes

    int count = 0;
#pragma unroll
    for (int t = 0; t < TSPLIT; ++t) count += cntPart[t * N_LAB + label];
    const float inv = 1.f / fmaxf((float)count, 1.f);

    f32x4 s = {0.f, 0.f, 0.f, 0.f};
#pragma unroll 8
    for (int t = 0; t < TSPLIT; ++t)
        s += *(const f32x4*)(part + ((size_t)t * N_LAB + label) * D_DIM + tid * 4);
    s *= inv;

    bf16x4 b;
    b[0] = (bf16_t)s[0]; b[1] = (bf16_t)s[1];
    b[2] = (bf16_t)s[2]; b[3] = (bf16_t)s[3];
    *(bf16x4*)(protoB + (size_t)label * D_DIM + tid * 4) = b;

    float ss = s[0]*s[0] + s[1]*s[1] + s[2]*s[2] + s[3]*s[3];
    for (int off = 32; off; off >>= 1) ss += __shfl_down(ss, off);
    if (lane == 0) red[wave] = ss;
    __syncthreads();
    if (tid < 4) p2part[label * 4 + tid] = red[tid]; // quarter q covers dims [q*256,(q+1)*256)
}

// ---------------- Kernel 2: logits via bf16 MFMA, K-split x4, mask-skip ---
// grid = 1024 blocks x 256 threads. Block covers 16 query rows x 64 labels;
// wave w handles K-quarter [w*256,(w+1)*256). Rows with q_mask==0 produce
// zero output, so their 4KB q_emb reads are skipped entirely (exec-masked
// loads; fragment zeroed) -> query HBM traffic ~halves.
// A frag: A[m=lane&15][k=quad*8+j]; B frag: B[k][n=lane&15];
// C/D: col=lane&15, row=quad*4+reg.
__global__ __launch_bounds__(256) void k_logits(
    const float* __restrict__ q_emb, const int* __restrict__ q_mask,
    const bf16_t* __restrict__ protoB, const float* __restrict__ p2part,
    float* __restrict__ out)
{
    __shared__ float red[4][64][16];
    __shared__ float q2red[4][16];

    const int tid  = threadIdx.x;
    const int wave = tid >> 6;          // k-quarter
    const int lane = tid & 63;
    const int r15  = lane & 15;
    const int quad = lane >> 4;
    const int m_base = blockIdx.x * 16;
    const int k0 = wave * 256;

    const int rowmask = q_mask[m_base + r15];

    const float*  aptr = q_emb  + (size_t)(m_base + r15) * D_DIM + k0 + quad * 8;
    const bf16_t* bptr = protoB + (size_t)r15 * D_DIM + k0 + quad * 8;

    f32x4 acc[4] = {};
    float q2p = 0.f;

#pragma unroll 4
    for (int kk = 0; kk < 256; kk += 32) {
        f32x4 a0 = {0.f, 0.f, 0.f, 0.f};
        f32x4 a1 = {0.f, 0.f, 0.f, 0.f};
        if (rowmask) {
            a0 = *(const f32x4*)(aptr + kk);
            a1 = *(const f32x4*)(aptr + kk + 4);
        }
        bf16x8 af;
        af[0] = (bf16_t)a0[0]; af[1] = (bf16_t)a0[1];
        af[2] = (bf16_t)a0[2]; af[3] = (bf16_t)a0[3];
        af[4] = (bf16_t)a1[0]; af[5] = (bf16_t)a1[1];
        af[6] = (bf16_t)a1[2]; af[7] = (bf16_t)a1[3];
        q2p += a0[0]*a0[0] + a0[1]*a0[1] + a0[2]*a0[2] + a0[3]*a0[3]
             + a1[0]*a1[0] + a1[1]*a1[1] + a1[2]*a1[2] + a1[3]*a1[3];
#pragma unroll
        for (int t = 0; t < 4; ++t) {
            bf16x8 bfr = *(const bf16x8*)(bptr + (size_t)t * 16 * D_DIM + kk);
            acc[t] = __builtin_amdgcn_mfma_f32_16x16x32_bf16(af, bfr, acc[t], 0, 0, 0);
        }
    }

    // reduce q2 partial across the 4 quads (same r15)
    q2p += __shfl_xor(q2p, 16);
    q2p += __shfl_xor(q2p, 32);
    if (lane < 16) q2red[wave][lane] = q2p;

#pragma unroll
    for (int t = 0; t < 4; ++t) *(f32x4*)&red[wave][lane][t * 4] = acc[t];
    __syncthreads();

    // epilogue: thread = (l2 = tid&63, t = tid>>6); handles rows q2d*4+r, col t*16+c15
    const int l2  = tid & 63;
    const int c15 = l2 & 15;
    const int q2d = l2 >> 4;
    const int t   = tid >> 6;

    f32x4 sum = {};
#pragma unroll
    for (int w = 0; w < 4; ++w) sum += *(const f32x4*)&red[w][l2][t * 4];

    f32x4 pp = *(const f32x4*)(p2part + (size_t)(t * 16 + c15) * 4);
    const float p2v = pp[0] + pp[1] + pp[2] + pp[3];

#pragma unroll
    for (int r = 0; r < 4; ++r) {
        const int row = q2d * 4 + r;
        const float q2 = q2red[0][row] + q2red[1][row] + q2red[2][row] + q2red[3][row];
        const int gm = m_base + row;
        const float qm = (float)q_mask[gm];
        out[(size_t)gm * N_LAB + t * 16 + c15] = -(q2 + p2v - 2.f * sum[r]) * qm;
    }
}

extern "C" void kernel_launch(void* const* d_in, const int* in_sizes, int n_in,
                              void* d_out, int out_size, void* d_ws, size_t ws_size,
                              hipStream_t stream) {
    const float* s_emb = (const float*)d_in[0];
    const int*   s_tag = (const int*)d_in[1];
    const int*   s_msk = (const int*)d_in[2];
    const float* q_emb = (const float*)d_in[3];
    const int*   q_msk = (const int*)d_in[4];
    (void)in_sizes; (void)n_in; (void)out_size; (void)ws_size;

    char* ws = (char*)d_ws;
    float*  part    = (float*)ws;                      // 32*64*1024*4 = 8 MiB
    int*    cntPart = (int*)(ws + 8388608);            // 32*64*4 = 8 KiB
    int*    done    = (int*)(ws + 8396800);            // 64*4 = 256 B
    bf16_t* protoB  = (bf16_t*)(ws + 8397056);         // 64*1024*2 = 128 KiB
    float*  p2part  = (float*)(ws + 8528128);          // 64*4*4 = 1 KiB

    hipMemsetAsync(done, 0, N_LAB * sizeof(int), stream);
    hipLaunchKernelGGL(k_proto, dim3(TSPLIT * N_LAB), dim3(256), 0, stream,
                       s_emb, s_tag, s_msk, part, cntPart, done, protoB, p2part);
    hipLaunchKernelGGL(k_logits, dim3(1024), dim3(256), 0, stream,
                       q_emb, q_msk, protoB, p2part, (float*)d_out);
}

// Round 6
// 169.249 us; speedup vs baseline: 2.7306x; 2.7306x over previous
//
#include <hip/hip_runtime.h>
#include <hip/hip_bf16.h>

typedef __bf16 bf16_t;
typedef __bf16 bf16x8 __attribute__((ext_vector_type(8)));
typedef __bf16 bf16x4 __attribute__((ext_vector_type(4)));
typedef float  f32x4  __attribute__((ext_vector_type(4)));

#define D_DIM 1024
#define N_LAB 64
#define ST_TOK 16384
#define QT_TOK 16384
#define TSPLIT 32
#define TSLICE (ST_TOK / TSPLIT)   // 512 tokens per slice

// ---------------- Kernel 1: proto partial sums (scan + stream) -----------
// grid = 2048 blocks: blockIdx = (ts<<6) | label. Each block scans its
// 512-token slice once for (mask && tag==label); the 256 threads then
// cooperatively stream each matching FULL row (thread owns dims tid*4..+3),
// accumulating in registers. One fp32 partial row + count per block.
// NOTE (R5 lesson): do NOT fuse the finalize via __threadfence+last-block —
// per-block device-scope fences force per-XCD L2 writebacks and serialized
// the kernel 20us -> 330us. The kernel boundary is the cheap fence.
__global__ __launch_bounds__(256) void k_proto(
    const float* __restrict__ s_emb, const int* __restrict__ tag,
    const int* __restrict__ msk, float* __restrict__ part,
    int* __restrict__ cntPart)
{
    __shared__ int list[TSLICE];
    __shared__ int cnt;

    const int tid   = threadIdx.x;
    const int label = blockIdx.x & 63;
    const int ts    = blockIdx.x >> 6;

    if (tid == 0) cnt = 0;
    __syncthreads();

    const int t0 = ts * TSLICE;
    for (int i = tid; i < TSLICE; i += 256) {
        const int t = t0 + i;
        if (msk[t] && tag[t] == label) list[atomicAdd(&cnt, 1)] = t;
    }
    __syncthreads();
    const int n = cnt;

    f32x4 acc = {0.f, 0.f, 0.f, 0.f};
    const float* base = s_emb + tid * 4;
    int i = 0;
    for (; i + 2 <= n; i += 2) {
        f32x4 v0 = *(const f32x4*)(base + (size_t)list[i]     * D_DIM);
        f32x4 v1 = *(const f32x4*)(base + (size_t)list[i + 1] * D_DIM);
        acc += v0;
        acc += v1;
    }
    if (i < n) acc += *(const f32x4*)(base + (size_t)list[i] * D_DIM);

    *(f32x4*)(part + ((size_t)ts * N_LAB + label) * D_DIM + tid * 4) = acc;
    if (tid == 0) cntPart[ts * N_LAB + label] = n;
}

// ---------------- Kernel 2: finalize protos ------------------------------
// 64 blocks (one per label) x 256 threads; thread sums 32 partials for its
// 4 dims, divides by count, writes bf16 proto + per-quarter p2 partials.
__global__ __launch_bounds__(256) void k_pfinal(
    const float* __restrict__ part, const int* __restrict__ cntPart,
    bf16_t* __restrict__ protoB, float* __restrict__ p2part)
{
    const int label = blockIdx.x;
    const int tid   = threadIdx.x;
    const int lane  = tid & 63;
    const int wave  = tid >> 6;

    int count = 0;
#pragma unroll
    for (int t = 0; t < TSPLIT; ++t) count += cntPart[t * N_LAB + label];
    const float inv = 1.f / fmaxf((float)count, 1.f);

    f32x4 s = {0.f, 0.f, 0.f, 0.f};
#pragma unroll 8
    for (int t = 0; t < TSPLIT; ++t)
        s += *(const f32x4*)(part + ((size_t)t * N_LAB + label) * D_DIM + tid * 4);
    s *= inv;

    bf16x4 b;
    b[0] = (bf16_t)s[0]; b[1] = (bf16_t)s[1];
    b[2] = (bf16_t)s[2]; b[3] = (bf16_t)s[3];
    *(bf16x4*)(protoB + (size_t)label * D_DIM + tid * 4) = b;

    float ss = s[0]*s[0] + s[1]*s[1] + s[2]*s[2] + s[3]*s[3];
    for (int off = 32; off; off >>= 1) ss += __shfl_down(ss, off);
    if (lane == 0) p2part[label * 4 + wave] = ss;   // wave w covers dims [w*256,(w+1)*256)
}

// ---------------- Kernel 3: logits via bf16 MFMA, K-split x4, mask-skip ---
// grid = 1024 blocks x 256 threads. Block covers 16 query rows x 64 labels;
// wave w handles K-quarter [w*256,(w+1)*256). Rows with q_mask==0 produce
// zero output, so their 4KB q_emb reads are skipped (exec-masked loads,
// zeroed fragment) -> query HBM traffic ~halves.
// A frag: A[m=lane&15][k=quad*8+j]; B frag: B[k][n=lane&15];
// C/D: col=lane&15, row=quad*4+reg.
__global__ __launch_bounds__(256) void k_logits(
    const float* __restrict__ q_emb, const int* __restrict__ q_mask,
    const bf16_t* __restrict__ protoB, const float* __restrict__ p2part,
    float* __restrict__ out)
{
    __shared__ float red[4][64][16];
    __shared__ float q2red[4][16];

    const int tid  = threadIdx.x;
    const int wave = tid >> 6;          // k-quarter
    const int lane = tid & 63;
    const int r15  = lane & 15;
    const int quad = lane >> 4;
    const int m_base = blockIdx.x * 16;
    const int k0 = wave * 256;

    const int rowmask = q_mask[m_base + r15];

    const float*  aptr = q_emb  + (size_t)(m_base + r15) * D_DIM + k0 + quad * 8;
    const bf16_t* bptr = protoB + (size_t)r15 * D_DIM + k0 + quad * 8;

    f32x4 acc[4] = {};
    float q2p = 0.f;

#pragma unroll 4
    for (int kk = 0; kk < 256; kk += 32) {
        f32x4 a0 = {0.f, 0.f, 0.f, 0.f};
        f32x4 a1 = {0.f, 0.f, 0.f, 0.f};
        if (rowmask) {
            a0 = *(const f32x4*)(aptr + kk);
            a1 = *(const f32x4*)(aptr + kk + 4);
        }
        bf16x8 af;
        af[0] = (bf16_t)a0[0]; af[1] = (bf16_t)a0[1];
        af[2] = (bf16_t)a0[2]; af[3] = (bf16_t)a0[3];
        af[4] = (bf16_t)a1[0]; af[5] = (bf16_t)a1[1];
        af[6] = (bf16_t)a1[2]; af[7] = (bf16_t)a1[3];
        q2p += a0[0]*a0[0] + a0[1]*a0[1] + a0[2]*a0[2] + a0[3]*a0[3]
             + a1[0]*a1[0] + a1[1]*a1[1] + a1[2]*a1[2] + a1[3]*a1[3];
#pragma unroll
        for (int t = 0; t < 4; ++t) {
            bf16x8 bfr = *(const bf16x8*)(bptr + (size_t)t * 16 * D_DIM + kk);
            acc[t] = __builtin_amdgcn_mfma_f32_16x16x32_bf16(af, bfr, acc[t], 0, 0, 0);
        }
    }

    // reduce q2 partial across the 4 quads (same r15)
    q2p += __shfl_xor(q2p, 16);
    q2p += __shfl_xor(q2p, 32);
    if (lane < 16) q2red[wave][lane] = q2p;

#pragma unroll
    for (int t = 0; t < 4; ++t) *(f32x4*)&red[wave][lane][t * 4] = acc[t];
    __syncthreads();

    // epilogue: thread = (l2 = tid&63, t = tid>>6); handles rows q2d*4+r, col t*16+c15
    const int l2  = tid & 63;
    const int c15 = l2 & 15;
    const int q2d = l2 >> 4;
    const int t   = tid >> 6;

    f32x4 sum = {};
#pragma unroll
    for (int w = 0; w < 4; ++w) sum += *(const f32x4*)&red[w][l2][t * 4];

    f32x4 pp = *(const f32x4*)(p2part + (size_t)(t * 16 + c15) * 4);
    const float p2v = pp[0] + pp[1] + pp[2] + pp[3];

#pragma unroll
    for (int r = 0; r < 4; ++r) {
        const int row = q2d * 4 + r;
        const float q2 = q2red[0][row] + q2red[1][row] + q2red[2][row] + q2red[3][row];
        const int gm = m_base + row;
        const float qm = (float)q_mask[gm];
        out[(size_t)gm * N_LAB + t * 16 + c15] = -(q2 + p2v - 2.f * sum[r]) * qm;
    }
}

extern "C" void kernel_launch(void* const* d_in, const int* in_sizes, int n_in,
                              void* d_out, int out_size, void* d_ws, size_t ws_size,
                              hipStream_t stream) {
    const float* s_emb = (const float*)d_in[0];
    const int*   s_tag = (const int*)d_in[1];
    const int*   s_msk = (const int*)d_in[2];
    const float* q_emb = (const float*)d_in[3];
    const int*   q_msk = (const int*)d_in[4];
    (void)in_sizes; (void)n_in; (void)out_size; (void)ws_size;

    char* ws = (char*)d_ws;
    float*  part    = (float*)ws;                      // 32*64*1024*4 = 8 MiB
    int*    cntPart = (int*)(ws + 8388608);            // 32*64*4 = 8 KiB
    bf16_t* protoB  = (bf16_t*)(ws + 8396800);         // 64*1024*2 = 128 KiB
    float*  p2part  = (float*)(ws + 8527872);          // 64*4*4 = 1 KiB

    hipLaunchKernelGGL(k_proto, dim3(TSPLIT * N_LAB), dim3(256), 0, stream,
                       s_emb, s_tag, s_msk, part, cntPart);
    hipLaunchKernelGGL(k_pfinal, dim3(64), dim3(256), 0, stream,
                       part, cntPart, protoB, p2part);
    hipLaunchKernelGGL(k_logits, dim3(1024), dim3(256), 0, stream,
                       q_emb, q_msk, protoB, p2part, (float*)d_out);
}

// Round 7
// 166.236 us; speedup vs baseline: 2.7801x; 1.0181x over previous
//
#include <hip/hip_runtime.h>
#include <hip/hip_bf16.h>

typedef __bf16 bf16_t;
typedef __bf16 bf16x8 __attribute__((ext_vector_type(8)));
typedef __bf16 bf16x4 __attribute__((ext_vector_type(4)));
typedef float  f32x4  __attribute__((ext_vector_type(4)));

#define D_DIM 1024
#define N_LAB 64
#define ST_TOK 16384
#define QT_TOK 16384
#define TSPLIT 32
#define TSLICE (ST_TOK / TSPLIT)   // 512 tokens per slice

// ---------------- Kernel 1: proto partial sums (scan + stream) -----------
// grid = 2048 blocks: blockIdx = (ts<<6) | label. Each block scans its
// 512-token slice once for (mask && tag==label); the 256 threads then
// cooperatively stream each matching FULL row (thread owns dims tid*4..+3),
// accumulating in fp32 registers; partial row stored as bf16 (halves part
// traffic; bf16 round-off on ~3-magnitude partials is ~0.01, negligible vs
// the 25.3 threshold). One partial row + count per block. 8 blocks/CU.
// NOTE (R5 lesson): do NOT fuse the finalize via __threadfence+last-block —
// per-block device-scope fences force per-XCD L2 writebacks (20us -> 330us).
__global__ __launch_bounds__(256) void k_proto(
    const float* __restrict__ s_emb, const int* __restrict__ tag,
    const int* __restrict__ msk, bf16_t* __restrict__ part,
    int* __restrict__ cntPart)
{
    __shared__ int list[TSLICE];
    __shared__ int cnt;

    const int tid   = threadIdx.x;
    const int label = blockIdx.x & 63;
    const int ts    = blockIdx.x >> 6;

    if (tid == 0) cnt = 0;
    __syncthreads();

    const int t0 = ts * TSLICE;
    for (int i = tid; i < TSLICE; i += 256) {
        const int t = t0 + i;
        if (msk[t] && tag[t] == label) list[atomicAdd(&cnt, 1)] = t;
    }
    __syncthreads();
    const int n = cnt;

    f32x4 acc = {0.f, 0.f, 0.f, 0.f};
    const float* base = s_emb + tid * 4;
    int i = 0;
    for (; i + 2 <= n; i += 2) {
        f32x4 v0 = *(const f32x4*)(base + (size_t)list[i]     * D_DIM);
        f32x4 v1 = *(const f32x4*)(base + (size_t)list[i + 1] * D_DIM);
        acc += v0;
        acc += v1;
    }
    if (i < n) acc += *(const f32x4*)(base + (size_t)list[i] * D_DIM);

    bf16x4 pb;
    pb[0] = (bf16_t)acc[0]; pb[1] = (bf16_t)acc[1];
    pb[2] = (bf16_t)acc[2]; pb[3] = (bf16_t)acc[3];
    *(bf16x4*)(part + ((size_t)ts * N_LAB + label) * D_DIM + tid * 4) = pb;
    if (tid == 0) cntPart[ts * N_LAB + label] = n;
}

// ---------------- Kernel 2: finalize protos ------------------------------
// 64 blocks (one per label) x 256 threads; thread sums 32 bf16 partials for
// its 4 dims in fp32, divides by count, writes bf16 proto + p2 partials.
__global__ __launch_bounds__(256) void k_pfinal(
    const bf16_t* __restrict__ part, const int* __restrict__ cntPart,
    bf16_t* __restrict__ protoB, float* __restrict__ p2part)
{
    const int label = blockIdx.x;
    const int tid   = threadIdx.x;
    const int lane  = tid & 63;
    const int wave  = tid >> 6;

    int count = 0;
#pragma unroll
    for (int t = 0; t < TSPLIT; ++t) count += cntPart[t * N_LAB + label];
    const float inv = 1.f / fmaxf((float)count, 1.f);

    f32x4 s = {0.f, 0.f, 0.f, 0.f};
#pragma unroll 8
    for (int t = 0; t < TSPLIT; ++t) {
        bf16x4 pv = *(const bf16x4*)(part + ((size_t)t * N_LAB + label) * D_DIM + tid * 4);
        s[0] += (float)pv[0]; s[1] += (float)pv[1];
        s[2] += (float)pv[2]; s[3] += (float)pv[3];
    }
    s *= inv;

    bf16x4 b;
    b[0] = (bf16_t)s[0]; b[1] = (bf16_t)s[1];
    b[2] = (bf16_t)s[2]; b[3] = (bf16_t)s[3];
    *(bf16x4*)(protoB + (size_t)label * D_DIM + tid * 4) = b;

    float ss = s[0]*s[0] + s[1]*s[1] + s[2]*s[2] + s[3]*s[3];
    for (int off = 32; off; off >>= 1) ss += __shfl_down(ss, off);
    if (lane == 0) p2part[label * 4 + wave] = ss;   // wave w covers dims [w*256,(w+1)*256)
}

// ---------------- Kernel 3: logits via bf16 MFMA, K-split x4 -------------
// grid = 1024 blocks x 256 threads. Block covers 16 query rows x 64 labels;
// wave w handles K-quarter [w*256,(w+1)*256). LDS-reduce the 4 partial
// accumulators + q2 partials, then epilogue. 4 blocks/CU -> 16 waves/CU.
// (R6 lesson: mask-skip on q_emb reads was neutral -> kernel is VALU/latency
// bound, not HBM bound; the branch is removed again.)
// A frag: A[m=lane&15][k=quad*8+j]; B frag: B[k][n=lane&15];
// C/D: col=lane&15, row=quad*4+reg.
__global__ __launch_bounds__(256) void k_logits(
    const float* __restrict__ q_emb, const int* __restrict__ q_mask,
    const bf16_t* __restrict__ protoB, const float* __restrict__ p2part,
    float* __restrict__ out)
{
    __shared__ float red[4][64][16];
    __shared__ float q2red[4][16];

    const int tid  = threadIdx.x;
    const int wave = tid >> 6;          // k-quarter
    const int lane = tid & 63;
    const int r15  = lane & 15;
    const int quad = lane >> 4;
    const int m_base = blockIdx.x * 16;
    const int k0 = wave * 256;

    const float*  aptr = q_emb  + (size_t)(m_base + r15) * D_DIM + k0 + quad * 8;
    const bf16_t* bptr = protoB + (size_t)r15 * D_DIM + k0 + quad * 8;

    f32x4 acc[4] = {};
    float q2p = 0.f;

#pragma unroll 4
    for (int kk = 0; kk < 256; kk += 32) {
        f32x4 a0 = *(const f32x4*)(aptr + kk);
        f32x4 a1 = *(const f32x4*)(aptr + kk + 4);
        bf16x8 af;
        af[0] = (bf16_t)a0[0]; af[1] = (bf16_t)a0[1];
        af[2] = (bf16_t)a0[2]; af[3] = (bf16_t)a0[3];
        af[4] = (bf16_t)a1[0]; af[5] = (bf16_t)a1[1];
        af[6] = (bf16_t)a1[2]; af[7] = (bf16_t)a1[3];
        q2p += a0[0]*a0[0] + a0[1]*a0[1] + a0[2]*a0[2] + a0[3]*a0[3]
             + a1[0]*a1[0] + a1[1]*a1[1] + a1[2]*a1[2] + a1[3]*a1[3];
#pragma unroll
        for (int t = 0; t < 4; ++t) {
            bf16x8 bfr = *(const bf16x8*)(bptr + (size_t)t * 16 * D_DIM + kk);
            acc[t] = __builtin_amdgcn_mfma_f32_16x16x32_bf16(af, bfr, acc[t], 0, 0, 0);
        }
    }

    // reduce q2 partial across the 4 quads (same r15)
    q2p += __shfl_xor(q2p, 16);
    q2p += __shfl_xor(q2p, 32);
    if (lane < 16) q2red[wave][lane] = q2p;

#pragma unroll
    for (int t = 0; t < 4; ++t) *(f32x4*)&red[wave][lane][t * 4] = acc[t];
    __syncthreads();

    // epilogue: thread = (l2 = tid&63, t = tid>>6); handles rows q2d*4+r, col t*16+c15
    const int l2  = tid & 63;
    const int c15 = l2 & 15;
    const int q2d = l2 >> 4;
    const int t   = tid >> 6;

    f32x4 sum = {};
#pragma unroll
    for (int w = 0; w < 4; ++w) sum += *(const f32x4*)&red[w][l2][t * 4];

    f32x4 pp = *(const f32x4*)(p2part + (size_t)(t * 16 + c15) * 4);
    const float p2v = pp[0] + pp[1] + pp[2] + pp[3];

#pragma unroll
    for (int r = 0; r < 4; ++r) {
        const int row = q2d * 4 + r;
        const float q2 = q2red[0][row] + q2red[1][row] + q2red[2][row] + q2red[3][row];
        const int gm = m_base + row;
        const float qm = (float)q_mask[gm];
        out[(size_t)gm * N_LAB + t * 16 + c15] = -(q2 + p2v - 2.f * sum[r]) * qm;
    }
}

extern "C" void kernel_launch(void* const* d_in, const int* in_sizes, int n_in,
                              void* d_out, int out_size, void* d_ws, size_t ws_size,
                              hipStream_t stream) {
    const float* s_emb = (const float*)d_in[0];
    const int*   s_tag = (const int*)d_in[1];
    const int*   s_msk = (const int*)d_in[2];
    const float* q_emb = (const float*)d_in[3];
    const int*   q_msk = (const int*)d_in[4];
    (void)in_sizes; (void)n_in; (void)out_size; (void)ws_size;

    char* ws = (char*)d_ws;
    bf16_t* part    = (bf16_t*)ws;                     // 32*64*1024*2 = 4 MiB
    int*    cntPart = (int*)(ws + 4194304);            // 32*64*4 = 8 KiB
    bf16_t* protoB  = (bf16_t*)(ws + 4202496);         // 64*1024*2 = 128 KiB
    float*  p2part  = (float*)(ws + 4333568);          // 64*4*4 = 1 KiB

    hipLaunchKernelGGL(k_proto, dim3(TSPLIT * N_LAB), dim3(256), 0, stream,
                       s_emb, s_tag, s_msk, part, cntPart);
    hipLaunchKernelGGL(k_pfinal, dim3(64), dim3(256), 0, stream,
                       part, cntPart, protoB, p2part);
    hipLaunchKernelGGL(k_logits, dim3(1024), dim3(256), 0, stream,
                       q_emb, q_msk, protoB, p2part, (float*)d_out);
}